// Round 7
// baseline (1256.693 us; speedup 1.0000x reference)
//
#include <hip/hip_runtime.h>
#include <hip/hip_bf16.h>

#define N_MOLS      64
#define N_CONFS_PER 10
#define A_ATOMS     40
#define N_CONFS     640
#define N_ATOMS     25600
#define N_EDGES     409600
#define D           256
#define NG          32
#define NLAYERS     4
#define MOLB        512
#define H_MOL       384
#define EDGE_CAP    1024
#define EB          64    // edge batch
#define SHBP        36    // sHb row stride (halfwords)
#define SEGP        40    // sEGb row stride (halfwords), 80B rows -> b128-aligned
#define LCAP        20    // per-atom incidence capacity per 64-edge batch
#define SRP         260   // padded fp32 LDS row stride (dwords)

typedef __attribute__((ext_vector_type(8))) short bshort8;
typedef __attribute__((ext_vector_type(4))) float f32x4;

__device__ __forceinline__ float sspf(float x) {
    return fmaxf(x, 0.f) + log1pf(expf(-fabsf(x))) - 0.69314718055994531f;
}
__device__ __forceinline__ float b2f(short s) {
    union { unsigned u; float f; } u;
    u.u = ((unsigned)(unsigned short)s) << 16;
    return u.f;
}
__device__ __forceinline__ short f2b(float x) {
    __hip_bfloat16 h = __float2bfloat16(x);
    return *reinterpret_cast<short*>(&h);
}

// pack 8 consecutive fp32 -> bf16x8 fragment
__device__ __forceinline__ bshort8 cvt8(const float* __restrict__ p) {
    const float4 lo = *(const float4*)p;
    const float4 hi = *(const float4*)(p + 4);
    union { bshort8 s; __hip_bfloat16 h[8]; } u;
    u.h[0] = __float2bfloat16(lo.x); u.h[1] = __float2bfloat16(lo.y);
    u.h[2] = __float2bfloat16(lo.z); u.h[3] = __float2bfloat16(lo.w);
    u.h[4] = __float2bfloat16(hi.x); u.h[5] = __float2bfloat16(hi.y);
    u.h[6] = __float2bfloat16(hi.z); u.h[7] = __float2bfloat16(hi.w);
    return u.s;
}

// ---------------- weight prep: dense W[l][k][n] fp32 -> WT[mat][l][n][k] bf16 ----------------
__global__ __launch_bounds__(256) void k_prep(const float* __restrict__ Wn,
                                              const float* __restrict__ Wu1,
                                              const float* __restrict__ Wu2,
                                              __hip_bfloat16* __restrict__ WT) {
    int idx = blockIdx.x * 256 + threadIdx.x;       // 3*4*256*256
    int k = idx & 255;
    int n = (idx >> 8) & 255;
    int l = (idx >> 16) & 3;
    int mat = idx >> 18;
    const float* src = (mat == 0) ? Wn : (mat == 1) ? Wu1 : Wu2;
    WT[idx] = __float2bfloat16(src[((size_t)l * 256 + k) * 256 + n]);
}

// WT2[l][n][k] bf16 from We2[l][k][n]; We1T[l][t][m] bf16 from We1[l][m][t]
__global__ __launch_bounds__(256) void k_prep2(const float* __restrict__ We2,
                                               const float* __restrict__ We1,
                                               __hip_bfloat16* __restrict__ WT2,
                                               __hip_bfloat16* __restrict__ We1T) {
    int idx = blockIdx.x * 256 + threadIdx.x;       // 32768 + 4096
    if (idx < 32768) {
        int k = idx & 31;
        int n = (idx >> 5) & 255;
        int l = idx >> 13;
        WT2[idx] = __float2bfloat16(We2[((size_t)l * 32 + k) * 256 + n]);
    } else {
        int j = idx - 32768;
        int m = j & 31;
        int t = (j >> 5) & 31;
        int l = j >> 10;
        We1T[j] = __float2bfloat16(We1[((size_t)l * 32 + m) * 32 + t]);
    }
}

// ---------------- edge bucketing by conformer ----------------
__global__ __launch_bounds__(256) void k_scatter(const int* __restrict__ nbr,
                                                 unsigned* __restrict__ cursors,
                                                 unsigned* __restrict__ esort) {
    int e = blockIdx.x * 256 + threadIdx.x;
    if (e >= N_EDGES) return;
    int a0 = nbr[2 * e], a1 = nbr[2 * e + 1];
    int conf = a0 / A_ATOMS;
    int a0l = a0 - conf * A_ATOMS;
    int a1l = a1 - conf * A_ATOMS;
    unsigned r = atomicAdd(&cursors[conf], 1u);
    if (r < EDGE_CAP) esort[conf * EDGE_CAP + r] = (unsigned)((a0l << 6) | a1l);
}

// dense MFMA, 12-wave split: wave -> (mt = wv>>2, nt0 = (wv&3)*4), 4 n-tiles
__device__ __forceinline__ void mfma_dense12(const float* __restrict__ src,
                                             const __hip_bfloat16* __restrict__ WT,
                                             f32x4 acc[4], int lane, int mt, int nt0) {
    const int r = lane & 15, g = lane >> 4;
#pragma unroll
    for (int j = 0; j < 4; ++j) acc[j] = (f32x4){0.f, 0.f, 0.f, 0.f};
#pragma unroll 2
    for (int kt = 0; kt < 8; ++kt) {
        const int ko = kt * 32 + g * 8;
        bshort8 a = cvt8(&src[(mt * 16 + r) * SRP + ko]);
#pragma unroll
        for (int j = 0; j < 4; ++j) {
            bshort8 b = *(const bshort8*)&WT[((nt0 + j) * 16 + r) * 256 + ko];
            acc[j] = __builtin_amdgcn_mfma_f32_16x16x32_bf16(a, b, acc[j], 0, 0, 0);
        }
    }
}

// writeback: MODE 0: dst = acc+bias ; 1: dst = ssp(acc+bias) ; 2: dst += acc+bias
template <int MODE>
__device__ __forceinline__ void mfma_wb12(const f32x4 acc[4], float* __restrict__ dst,
                                          const float* __restrict__ bias,
                                          int lane, int mt, int nt0) {
    const int cc = lane & 15, g = lane >> 4;
    const int cr = g * 4;
    if (mt == 2 && g >= 2) return;   // rows 40..47 are padding
#pragma unroll
    for (int j = 0; j < 4; ++j) {
        const int col = (nt0 + j) * 16 + cc;
        const float bv = bias[col];
#pragma unroll
        for (int reg = 0; reg < 4; ++reg) {
            const int row = mt * 16 + cr + reg;
            float v = acc[j][reg] + bv;
            if (MODE == 1) v = sspf(v);
            if (MODE == 2) v += dst[row * SRP + col];
            dst[row * SRP + col] = v;
        }
    }
}

// ---------------- main per-conformer kernel: 1024 threads, 16 waves ----------------
__global__ __launch_bounds__(1024, 4) void k_main(
    const int* __restrict__ z, const float* __restrict__ xyz,
    const float* __restrict__ emb,
    const float* __restrict__ be1, const float* __restrict__ be2,
    const float* __restrict__ bn,
    const float* __restrict__ bu1, const float* __restrict__ bu2,
    const __hip_bfloat16* __restrict__ WT,
    const __hip_bfloat16* __restrict__ WT2,
    const __hip_bfloat16* __restrict__ We1T,
    const unsigned* __restrict__ cursors, const unsigned* __restrict__ esort,
    float* __restrict__ conf_fp)
{
    __shared__ float sR[48 * SRP];         // residual r (49.9KB)
    __shared__ float sB[48 * SRP];         // rn -> agg -> t (49.9KB)
    __shared__ short sEFs[EB * 256];       // ef batch bf16 (32KB)
    __shared__ short sEGb[EB * SEGP];      // e_g batch bf16 [edge][m] (5KB)
    __shared__ short sHb[EB * SHBP];       // h batch bf16 [edge][t] (4.5KB)
    __shared__ int   sList[A_ATOMS * LCAP];
    __shared__ int   sCnt[A_ATOMS];
    __shared__ float sXYZ[A_ATOMS][3];
    __shared__ int   sE0[EB], sE1[EB];
    __shared__ float sDall[EDGE_CAP];      // scaled distances (4KB)
    __shared__ int   sZ[A_ATOMS];

    const int tid  = threadIdx.x;
    const int lane = tid & 63;
    const int wv   = tid >> 6;        // 0..15
    const int c4   = lane << 2;       // 0..252
    const int conf = blockIdx.x;
    const int mt_d  = wv >> 2;        // dense: m-tile (wv<12)
    const int nt0_d = (wv & 3) * 4;   // dense: first n-tile

    if (tid < A_ATOMS) {
        int ga = conf * A_ATOMS + tid;
        sZ[tid] = z[ga];
        sXYZ[tid][0] = xyz[ga * 3 + 0];
        sXYZ[tid][1] = xyz[ga * 3 + 1];
        sXYZ[tid][2] = xyz[ga * 3 + 2];
    }
    for (int i = tid; i < 8 * SRP; i += 1024) {   // zero pad rows 40..47
        sR[40 * SRP + i] = 0.f;
        sB[40 * SRP + i] = 0.f;
    }
    __syncthreads();
    {   // embedding init: quarter q handles 10 atoms
        const int c = tid & 255, q = tid >> 8;
#pragma unroll
        for (int a = 0; a < 10; ++a) {
            int aa = q * 10 + a;
            sR[aa * SRP + c] = emb[sZ[aa] * D + c];
        }
    }
    int cnt = (int)cursors[conf];
    if (cnt > EDGE_CAP) cnt = EDGE_CAP;
    const unsigned* eptr = esort + conf * EDGE_CAP;
    for (int i = tid; i < cnt; i += 1024) {
        unsigned pe = eptr[i];
        int a0l = (pe >> 6) & 63, a1l = pe & 63;
        float dx = sXYZ[a0l][0] - sXYZ[a1l][0];
        float dy = sXYZ[a0l][1] - sXYZ[a1l][1];
        float dz = sXYZ[a0l][2] - sXYZ[a1l][2];
        sDall[i] = sqrtf(dx * dx + dy * dy + dz * dz) * (31.0f / 5.0f);
    }

    // per-lane fragment constants
    const int fr = lane & 15, fg = lane >> 4, g8 = (lane >> 4) << 3;
    const int ntx = (wv >> 2) & 1;    // X2: n-tile (wv<8), mtx = wv&3

    for (int l = 0; l < NLAYERS; ++l) {
        __syncthreads();
        // ---- M1: sB = r @ Wn + bn
        {
            f32x4 acc[4];
            if (wv < 12) {
                mfma_dense12(sR, WT + ((size_t)(0 * 4 + l) << 16), acc, lane, mt_d, nt0_d);
                mfma_wb12<0>(acc, sB, bn + l * D, lane, mt_d, nt0_d);
            }
        }
        __syncthreads();
        // ---- edge phase
        float4 agg[3];
#pragma unroll
        for (int a = 0; a < 3; ++a) agg[a] = make_float4(0.f, 0.f, 0.f, 0.f);
        {
            // per-layer hoisted fragments
            const float be1t = be1[l * NG + ntx * 16 + fr];
            const bshort8 bfragX2 = *(const bshort8*)&We1T[(size_t)l * 1024 + (ntx * 16 + fr) * 32 + g8];
            const float be2w = be2[l * D + wv * 16 + fr];
            const bshort8 bfragP4 = *(const bshort8*)&WT2[(size_t)l * 8192 + (wv * 16 + fr) * 32 + g8];

            for (int base = 0; base < cnt; base += EB) {
                const int nb = min(EB, cnt - base);
                // X1: endpoints + zero counters + e_g (bf16, [edge][m])
                if (tid < nb) {
                    unsigned pe = eptr[base + tid];
                    sE0[tid] = (pe >> 6) & 63;
                    sE1[tid] = pe & 63;
                }
                if (tid >= 128 && tid < 128 + A_ATOMS) sCnt[tid - 128] = 0;
                {
                    const int e = tid >> 4;
                    const int m0 = (tid & 15) << 1;
                    float dd = sDall[base + e];
                    float u0 = dd - (float)(m0 + 0);
                    float u1 = dd - (float)(m0 + 1);
                    unsigned lo = (unsigned)(unsigned short)f2b(expf(-0.5f * u0 * u0));
                    unsigned hi = (unsigned)(unsigned short)f2b(expf(-0.5f * u1 * u1));
                    *(unsigned*)&sEGb[e * SEGP + m0] = lo | (hi << 16);
                }
                __syncthreads();
                // X2: incidence lists + h = ssp(e_g @ We1 + be1) via MFMA (waves 0..7)
                if (tid < nb) {
                    int a0 = sE0[tid], a1 = sE1[tid];
                    int i0 = atomicAdd(&sCnt[a0], 1);
                    if (i0 < LCAP) sList[a0 * LCAP + i0] = (a1 << 8) | tid;
                    int i1 = atomicAdd(&sCnt[a1], 1);
                    if (i1 < LCAP) sList[a1 * LCAP + i1] = (a0 << 8) | tid;
                }
                if (wv < 8) {
                    const int mtx = wv & 3;
                    bshort8 a = *(const bshort8*)&sEGb[(mtx * 16 + fr) * SEGP + g8];
                    f32x4 c = (f32x4){0.f, 0.f, 0.f, 0.f};
                    c = __builtin_amdgcn_mfma_f32_16x16x32_bf16(a, bfragX2, c, 0, 0, 0);
#pragma unroll
                    for (int reg = 0; reg < 4; ++reg) {
                        const int erow = mtx * 16 + fg * 4 + reg;
                        sHb[erow * SHBP + ntx * 16 + fr] = f2b(sspf(c[reg] + be1t));
                    }
                }
                __syncthreads();
                // P4: ef = h @ We2 + be2 via MFMA -> sEFs (wave wv: n-tile wv, all 4 mt)
                {
#pragma unroll
                    for (int mt = 0; mt < 4; ++mt) {
                        union { bshort8 v; short4 s[2]; } af;
                        af.s[0] = *(const short4*)&sHb[(mt * 16 + fr) * SHBP + g8];
                        af.s[1] = *(const short4*)&sHb[(mt * 16 + fr) * SHBP + g8 + 4];
                        f32x4 c = (f32x4){0.f, 0.f, 0.f, 0.f};
                        c = __builtin_amdgcn_mfma_f32_16x16x32_bf16(af.v, bfragP4, c, 0, 0, 0);
#pragma unroll
                        for (int reg = 0; reg < 4; ++reg) {
                            const int erow = mt * 16 + fg * 4 + reg;
                            if (erow < nb)
                                sEFs[erow * 256 + wv * 16 + fr] = f2b(c[reg] + be2w);
                        }
                    }
                }
                __syncthreads();
                // P5: gather into register agg (wave drains its 3 atoms)
#pragma unroll
                for (int a = 0; a < 3; ++a) {
                    const int row = wv * 3 + a;
                    if (row >= A_ATOMS) continue;
                    const int n = min(sCnt[row], LCAP);
                    for (int i = 0; i < n; ++i) {
                        const int ent = sList[row * LCAP + i];
                        const int e = ent & 255, o = ent >> 8;
                        const short4 f4 = *(const short4*)&sEFs[e * 256 + c4];
                        const float4 r4 = *(const float4*)&sB[o * SRP + c4];
                        agg[a].x = fmaf(b2f(f4.x), r4.x, agg[a].x);
                        agg[a].y = fmaf(b2f(f4.y), r4.y, agg[a].y);
                        agg[a].z = fmaf(b2f(f4.z), r4.z, agg[a].z);
                        agg[a].w = fmaf(b2f(f4.w), r4.w, agg[a].w);
                    }
                }
                __syncthreads();
            }
        }
        // agg -> sB (rn dead)
#pragma unroll
        for (int a = 0; a < 3; ++a) {
            const int row = wv * 3 + a;
            if (row < A_ATOMS) *(float4*)&sB[row * SRP + c4] = agg[a];
        }
        __syncthreads();
        // ---- M2: sB = ssp(agg @ Wu1 + bu1)  (in-place: sync between acc and wb)
        {
            f32x4 acc[4];
            if (wv < 12)
                mfma_dense12(sB, WT + ((size_t)(1 * 4 + l) << 16), acc, lane, mt_d, nt0_d);
            __syncthreads();
            if (wv < 12)
                mfma_wb12<1>(acc, sB, bu1 + l * D, lane, mt_d, nt0_d);
        }
        __syncthreads();
        // ---- M3: sR += t @ Wu2 + bu2
        {
            f32x4 acc[4];
            if (wv < 12) {
                mfma_dense12(sB, WT + ((size_t)(2 * 4 + l) << 16), acc, lane, mt_d, nt0_d);
                mfma_wb12<2>(acc, sR, bu2 + l * D, lane, mt_d, nt0_d);
            }
        }
    }
    __syncthreads();
    if (tid < D) {
        float s = 0.f;
#pragma unroll
        for (int a = 0; a < A_ATOMS; ++a) s += sR[a * SRP + tid];
        conf_fp[conf * D + tid] = s;
    }
}

// ---------------- per-conformer molecular MLP + Boltzmann-weighted reduce ----------------
__global__ __launch_bounds__(512) void k_mol(
    const float* __restrict__ conf_fp,
    const float* __restrict__ Wm1, const float* __restrict__ bm1,
    const float* __restrict__ Wm2, const float* __restrict__ bm2,
    const float* __restrict__ boltz, float* __restrict__ mol_fp)
{
    __shared__ float cf[D];
    __shared__ float t[H_MOL];
    const int conf = blockIdx.x;
    const int tid = threadIdx.x;
    if (tid < D) cf[tid] = conf_fp[conf * D + tid];
    __syncthreads();
    if (tid < H_MOL) {
        float s = bm1[tid];
        for (int k = 0; k < D; k += 4) {
            const float4 v = *(const float4*)&cf[k];
            s = fmaf(v.x, Wm1[(k + 0) * H_MOL + tid], s);
            s = fmaf(v.y, Wm1[(k + 1) * H_MOL + tid], s);
            s = fmaf(v.z, Wm1[(k + 2) * H_MOL + tid], s);
            s = fmaf(v.w, Wm1[(k + 3) * H_MOL + tid], s);
        }
        t[tid] = sspf(s);
    }
    __syncthreads();
    {
        const int m = tid;
        float s = bm2[m];
        for (int h = 0; h < H_MOL; h += 4) {
            const float4 v = *(const float4*)&t[h];
            s = fmaf(v.x, Wm2[(h + 0) * MOLB + m], s);
            s = fmaf(v.y, Wm2[(h + 1) * MOLB + m], s);
            s = fmaf(v.z, Wm2[(h + 2) * MOLB + m], s);
            s = fmaf(v.w, Wm2[(h + 3) * MOLB + m], s);
        }
        atomicAdd(&mol_fp[(conf / N_CONFS_PER) * MOLB + m], s * boltz[conf]);
    }
}

// ---------------- final readout MLP + sigmoid ----------------
__global__ __launch_bounds__(256) void k_final(
    const float* __restrict__ mol_fp,
    const float* __restrict__ Wr1, const float* __restrict__ br1,
    const float* __restrict__ Wr2, const float* __restrict__ br2,
    float* __restrict__ out)
{
    __shared__ float mf[MOLB];
    __shared__ float t2[D];
    __shared__ float red[4];
    const int mol = blockIdx.x, tid = threadIdx.x;
    mf[tid]       = mol_fp[mol * MOLB + tid];
    mf[tid + 256] = mol_fp[mol * MOLB + tid + 256];
    __syncthreads();
    {
        float s = br1[tid];
        for (int k = 0; k < MOLB; k += 4) {
            const float4 v = *(const float4*)&mf[k];
            s = fmaf(v.x, Wr1[(k + 0) * D + tid], s);
            s = fmaf(v.y, Wr1[(k + 1) * D + tid], s);
            s = fmaf(v.z, Wr1[(k + 2) * D + tid], s);
            s = fmaf(v.w, Wr1[(k + 3) * D + tid], s);
        }
        t2[tid] = sspf(s);
    }
    __syncthreads();
    float p = t2[tid] * Wr2[tid];
#pragma unroll
    for (int o = 32; o > 0; o >>= 1) p += __shfl_down(p, o);
    if ((tid & 63) == 0) red[tid >> 6] = p;
    __syncthreads();
    if (tid == 0) {
        float logit = red[0] + red[1] + red[2] + red[3] + br2[0];
        out[mol] = 1.f / (1.f + expf(-logit));
    }
}

extern "C" void kernel_launch(void* const* d_in, const int* in_sizes, int n_in,
                              void* d_out, int out_size, void* d_ws, size_t ws_size,
                              hipStream_t stream)
{
    const int*   z     = (const int*)d_in[0];
    const float* xyz   = (const float*)d_in[1];
    const int*   nbr   = (const int*)d_in[2];
    const float* boltz = (const float*)d_in[3];
    const float* emb   = (const float*)d_in[4];
    const float* We1   = (const float*)d_in[5];
    const float* be1   = (const float*)d_in[6];
    const float* We2   = (const float*)d_in[7];
    const float* be2   = (const float*)d_in[8];
    const float* Wn    = (const float*)d_in[9];
    const float* bn    = (const float*)d_in[10];
    const float* Wu1   = (const float*)d_in[11];
    const float* bu1   = (const float*)d_in[12];
    const float* Wu2   = (const float*)d_in[13];
    const float* bu2   = (const float*)d_in[14];
    const float* Wm1   = (const float*)d_in[15];
    const float* bm1   = (const float*)d_in[16];
    const float* Wm2   = (const float*)d_in[17];
    const float* bm2   = (const float*)d_in[18];
    const float* Wr1   = (const float*)d_in[19];
    const float* br1   = (const float*)d_in[20];
    const float* Wr2   = (const float*)d_in[21];
    const float* br2   = (const float*)d_in[22];

    char* ws = (char*)d_ws;
    unsigned* cursors        = (unsigned*)ws;                   // 2560 B
    float*    mol_fp         = (float*)(ws + 2560);             // 131072 B -> 133632
    unsigned* esort          = (unsigned*)(ws + 133632);        // 2621440 B -> 2755072
    float*    conf_fp        = (float*)(ws + 2755072);          // 655360 B -> 3410432
    __hip_bfloat16* WT       = (__hip_bfloat16*)(ws + 3410432); // 1572864 B -> 4983296
    __hip_bfloat16* WT2      = (__hip_bfloat16*)(ws + 4983296); // 65536 B -> 5048832
    __hip_bfloat16* We1T     = (__hip_bfloat16*)(ws + 5048832); // 8192 B -> 5057024

    hipMemsetAsync(cursors, 0, 2560 + 131072, stream);          // cursors + mol_fp
    k_prep<<<3072, 256, 0, stream>>>(Wn, Wu1, Wu2, WT);
    k_prep2<<<144, 256, 0, stream>>>(We2, We1, WT2, We1T);
    k_scatter<<<(N_EDGES + 255) / 256, 256, 0, stream>>>(nbr, cursors, esort);
    k_main<<<N_CONFS, 1024, 0, stream>>>(z, xyz, emb, be1, be2, bn,
                                         bu1, bu2, WT, WT2, We1T, cursors, esort, conf_fp);
    k_mol<<<N_CONFS, 512, 0, stream>>>(conf_fp, Wm1, bm1, Wm2, bm2, boltz, mol_fp);
    k_final<<<N_MOLS, 256, 0, stream>>>(mol_fp, Wr1, br1, Wr2, br2, (float*)d_out);
}